// Round 1
// baseline (1949.520 us; speedup 1.0000x reference)
//
#include <hip/hip_runtime.h>
#include <hip/hip_bf16.h>

// ---------------------------------------------------------------------------
// Hie_Couple: live subgraph only (xs_/A_s/C_M_S/bias_S/Vf are dead in ref).
// Pipeline:
//   Q=xs@wqs^T+bqs, K=xf@wkf^T+bkf, Vs=xs@wvs^T+bvs, Qf=xf@cfa_wq^T+..,
//   Kf=xs_fine@cfa_wk^T+..
//   C_M = Q K^T /16      -> d_out[2] (+ transposed copy CMT in ws)
//   S   = Qf Kf^T /16    -> entmax15 rows (Newton on sum relu(z-tau)^2=1)
//   BT  = P @ S_s        (== bias_F^T)
//   ZT  = CMT + log(max(BT,1e-6)) -> entmax rows == A_f^T
//   T1  = A_f^T @ Vs ; xf_ = T1@wof^T+bof -> d_out[1]
//   out0 = xf_ + LN(xf)  -> d_out[0]
// ---------------------------------------------------------------------------

#define BM 64
#define BN 64
#define BK 16

// TB==1: B is [N,K] row-major (C = A B^T). TB==0: B is [K,N] row-major.
template <int TB>
__global__ __launch_bounds__(256) void gemm_kernel(
    const float* __restrict__ A, const float* __restrict__ B,
    const float* __restrict__ bias, float* __restrict__ C,
    float* __restrict__ C2, int M, int N, int K,
    long sA, long sB, long sC, long sC2, float scale)
{
    const int bz = blockIdx.z;
    A += (long)bz * sA;
    B += (long)bz * sB;
    C += (long)bz * sC;
    if (C2) C2 += (long)bz * sC2;

    const int m0 = blockIdx.x * BM;
    const int n0 = blockIdx.y * BN;

    __shared__ float As[BK][BM + 4];
    __shared__ float Bs[BK][BN + 4];

    const int tid = threadIdx.x;
    const int tx = tid & 15;   // N micro index
    const int ty = tid >> 4;   // M micro index

    float acc[4][4] = {};

    for (int k0 = 0; k0 < K; k0 += BK) {
        // --- stage A tile: As[k][m] = A[(m0+m)*K + k0+k]
        {
            const int lk = tid & 15;
            const int lm = (tid >> 4) << 2;
            const float* Ap = A + (long)(m0 + lm) * K + (k0 + lk);
#pragma unroll
            for (int i = 0; i < 4; ++i) As[lk][lm + i] = Ap[(long)i * K];
        }
        // --- stage B tile
        if (TB == 1) {  // Bs[k][n] = B[(n0+n)*K + k0+k]
            const int lk = tid & 15;
            const int ln = (tid >> 4) << 2;
            const float* Bp = B + (long)(n0 + ln) * K + (k0 + lk);
#pragma unroll
            for (int i = 0; i < 4; ++i) Bs[lk][ln + i] = Bp[(long)i * K];
        } else {        // Bs[k][n] = B[(k0+k)*N + n0+n]
            const int ln = tid & 63;
            const int lk = (tid >> 6) << 2;
            const float* Bp = B + (long)(k0 + lk) * N + (n0 + ln);
#pragma unroll
            for (int i = 0; i < 4; ++i) Bs[lk + i][ln] = Bp[(long)i * N];
        }
        __syncthreads();

#pragma unroll
        for (int k = 0; k < BK; ++k) {
            const float4 av = *reinterpret_cast<const float4*>(&As[k][ty << 2]);
            const float4 bv = *reinterpret_cast<const float4*>(&Bs[k][tx << 2]);
            const float a[4] = {av.x, av.y, av.z, av.w};
            const float b[4] = {bv.x, bv.y, bv.z, bv.w};
#pragma unroll
            for (int i = 0; i < 4; ++i)
#pragma unroll
                for (int j = 0; j < 4; ++j) acc[i][j] += a[i] * b[j];
        }
        __syncthreads();
    }

#pragma unroll
    for (int i = 0; i < 4; ++i) {
        const int row = m0 + (ty << 2) + i;
#pragma unroll
        for (int j = 0; j < 4; ++j) {
            const int col = n0 + (tx << 2) + j;
            float v = acc[i][j] * scale;
            if (bias) v += bias[col];
            C[(long)row * N + col] = v;
            if (C2) C2[(long)col * M + row] = v;
        }
    }
}

// entmax-1.5 over rows of length L. If Bias != nullptr:
//   z = Zin + log(max(Bias, 1e-6)) elementwise, else z = Zin.
// Newton on f(tau) = sum relu((z-mx)/2 - tau)^2 = 1 from tau = -1 (monotone,
// convex f => no overshoot; identical tau* to the reference's sort form).
__global__ __launch_bounds__(256) void entmax_kernel(
    const float* __restrict__ Zin, const float* __restrict__ Bias,
    float* __restrict__ Out, int L)
{
    extern __shared__ float zb[];
    __shared__ float rbuf[8];
    const int tid = threadIdx.x;
    const long base = (long)blockIdx.x * L;

    float lmax = -3.4e38f;
    for (int i = tid; i < L; i += 256) {
        float z = Zin[base + i];
        if (Bias) z += logf(fmaxf(Bias[base + i], 1e-6f));
        zb[i] = z;
        lmax = fmaxf(lmax, z);
    }
    for (int o = 32; o > 0; o >>= 1) lmax = fmaxf(lmax, __shfl_down(lmax, o));
    if ((tid & 63) == 0) rbuf[tid >> 6] = lmax;
    __syncthreads();
    const float mx = fmaxf(fmaxf(rbuf[0], rbuf[1]), fmaxf(rbuf[2], rbuf[3]));

    for (int i = tid; i < L; i += 256) zb[i] = (zb[i] - mx) * 0.5f;
    __syncthreads();

    float tau = -1.0f;
    for (int it = 0; it < 40; ++it) {
        float f = 0.f, g = 0.f;
        for (int i = tid; i < L; i += 256) {
            float d = fmaxf(zb[i] - tau, 0.f);
            f += d * d;
            g += d;
        }
        for (int o = 32; o > 0; o >>= 1) {
            f += __shfl_down(f, o);
            g += __shfl_down(g, o);
        }
        __syncthreads();
        if ((tid & 63) == 0) {
            rbuf[(tid >> 6) * 2] = f;
            rbuf[(tid >> 6) * 2 + 1] = g;
        }
        __syncthreads();
        f = rbuf[0] + rbuf[2] + rbuf[4] + rbuf[6];
        g = rbuf[1] + rbuf[3] + rbuf[5] + rbuf[7];
        if (g <= 0.f) break;                 // uniform
        const float step = (f - 1.0f) / (2.0f * g);
        tau += step;
        if (fabsf(step) < 1e-8f) break;      // uniform
    }

    for (int i = tid; i < L; i += 256) {
        const float d = fmaxf(zb[i] - tau, 0.f);
        Out[base + i] = d * d;
    }
}

// out0[row,:] = xfo[row,:] + LayerNorm(xf[row,:]) * g + b   (D = 256, 1 block/row)
__global__ __launch_bounds__(256) void ln_add_kernel(
    const float* __restrict__ xf, const float* __restrict__ gam,
    const float* __restrict__ bet, const float* __restrict__ xfo,
    float* __restrict__ out0)
{
    __shared__ float rbuf[4];
    const int tid = threadIdx.x;
    const long base = (long)blockIdx.x * 256;
    const float x = xf[base + tid];

    float s = x;
    for (int o = 32; o > 0; o >>= 1) s += __shfl_down(s, o);
    if ((tid & 63) == 0) rbuf[tid >> 6] = s;
    __syncthreads();
    const float mu = (rbuf[0] + rbuf[1] + rbuf[2] + rbuf[3]) * (1.0f / 256.0f);
    const float d = x - mu;

    float v = d * d;
    for (int o = 32; o > 0; o >>= 1) v += __shfl_down(v, o);
    __syncthreads();
    if ((tid & 63) == 0) rbuf[tid >> 6] = v;
    __syncthreads();
    const float var = (rbuf[0] + rbuf[1] + rbuf[2] + rbuf[3]) * (1.0f / 256.0f);

    const float ln = d * rsqrtf(var + 1e-5f) * gam[tid] + bet[tid];
    out0[base + tid] = xfo[base + tid] + ln;
}

extern "C" void kernel_launch(void* const* d_in, const int* in_sizes, int n_in,
                              void* d_out, int out_size, void* d_ws, size_t ws_size,
                              hipStream_t stream)
{
    (void)in_sizes; (void)n_in; (void)out_size; (void)ws_size;

    const float* xs      = (const float*)d_in[0];
    const float* xf      = (const float*)d_in[1];
    const float* xs_fine = (const float*)d_in[2];
    const float* S_s     = (const float*)d_in[4];
    const float* cfa_wq  = (const float*)d_in[6];
    const float* cfa_bq  = (const float*)d_in[7];
    const float* cfa_wk  = (const float*)d_in[8];
    const float* cfa_bk  = (const float*)d_in[9];
    const float* wqs     = (const float*)d_in[14];
    const float* bqs     = (const float*)d_in[15];
    const float* wkf     = (const float*)d_in[16];
    const float* bkf     = (const float*)d_in[17];
    const float* wvs     = (const float*)d_in[18];
    const float* bvs     = (const float*)d_in[19];
    const float* wof     = (const float*)d_in[24];
    const float* bof     = (const float*)d_in[25];
    const float* fn_g    = (const float*)d_in[28];
    const float* fn_b    = (const float*)d_in[29];

    // workspace layout (floats); buffer reuse: BT over Kf, AfT over P, T1 over Q
    float* ws  = (float*)d_ws;
    float* Q   = ws + 0;          //  2,097,152
    float* Km  = ws + 2097152;    //  2,097,152
    float* Vs  = ws + 4194304;    //  2,097,152
    float* Qf  = ws + 6291456;    //  2,097,152
    float* Kf  = ws + 8388608;    //  8,388,608
    float* CMT = ws + 16777216;   //  8,388,608
    float* P   = ws + 25165824;   // 33,554,432  (peak: 58,720,256 floats = 224 MiB)
    float* BT  = Kf;              // Kf dead after scores GEMM
    float* AfT = P;               // P dead after BT GEMM
    float* T1  = Q;               // Q dead after C_M GEMM

    float* out0 = (float*)d_out;            // xs_out [8,1024,256]
    float* out1 = out0 + 2097152;           // xf_    [8,1024,256]
    float* outC = out0 + 4194304;           // C_M    [8,1024,1024]

    const dim3 blk(256);

    // 5 linears: Y = X @ W^T + b
    gemm_kernel<1><<<dim3(128, 4, 1), blk, 0, stream>>>(xs, wqs, bqs, Q, nullptr,
        8192, 256, 256, 0, 0, 0, 0, 1.f);
    gemm_kernel<1><<<dim3(128, 4, 1), blk, 0, stream>>>(xf, wkf, bkf, Km, nullptr,
        8192, 256, 256, 0, 0, 0, 0, 1.f);
    gemm_kernel<1><<<dim3(128, 4, 1), blk, 0, stream>>>(xs, wvs, bvs, Vs, nullptr,
        8192, 256, 256, 0, 0, 0, 0, 1.f);
    gemm_kernel<1><<<dim3(128, 4, 1), blk, 0, stream>>>(xf, cfa_wq, cfa_bq, Qf, nullptr,
        8192, 256, 256, 0, 0, 0, 0, 1.f);
    gemm_kernel<1><<<dim3(512, 4, 1), blk, 0, stream>>>(xs_fine, cfa_wk, cfa_bk, Kf, nullptr,
        32768, 256, 256, 0, 0, 0, 0, 1.f);

    // C_M = Q K^T / 16  (normal copy -> output, transposed copy -> CMT)
    gemm_kernel<1><<<dim3(16, 16, 8), blk, 0, stream>>>(Q, Km, nullptr, outC, CMT,
        1024, 1024, 256, 262144, 262144, 1048576, 1048576, 0.0625f);

    // scores = Qf Kf^T / 16 -> P  [8,1024,4096]
    gemm_kernel<1><<<dim3(16, 64, 8), blk, 0, stream>>>(Qf, Kf, nullptr, P, nullptr,
        1024, 4096, 256, 262144, 1048576, 4194304, 0, 0.0625f);

    // C_M_F = entmax15(scores) rows, in place
    entmax_kernel<<<dim3(8192), blk, 4096 * sizeof(float), stream>>>(P, nullptr, P, 4096);

    // BT = P @ S_s  (== bias_F^T)  [8,1024,1024], K = 4096
    gemm_kernel<0><<<dim3(16, 16, 8), blk, 0, stream>>>(P, S_s, nullptr, BT, nullptr,
        1024, 1024, 4096, 4194304, 4194304, 1048576, 0, 1.f);

    // A_f^T = entmax15(CMT + log(max(BT,1e-6))) rows
    entmax_kernel<<<dim3(8192), blk, 1024 * sizeof(float), stream>>>(CMT, BT, AfT, 1024);

    // T1 = A_f^T @ Vs  [8,1024,256], K = 1024
    gemm_kernel<0><<<dim3(16, 4, 8), blk, 0, stream>>>(AfT, Vs, nullptr, T1, nullptr,
        1024, 256, 1024, 1048576, 262144, 262144, 0, 1.f);

    // xf_ = T1 @ wof^T + bof -> out1
    gemm_kernel<1><<<dim3(128, 4, 1), blk, 0, stream>>>(T1, wof, bof, out1, nullptr,
        8192, 256, 256, 0, 0, 0, 0, 1.f);

    // out0 = out1 + LayerNorm(xf)
    ln_add_kernel<<<dim3(8192), blk, 0, stream>>>(xf, fn_g, fn_b, out1, out0);
}

// Round 2
// 975.229 us; speedup vs baseline: 1.9990x; 1.9990x over previous
//
#include <hip/hip_runtime.h>
#include <hip/hip_bf16.h>

// ---------------------------------------------------------------------------
// Hie_Couple live subgraph (xs_/A_s/C_M_S/bias_S/Vf dead in reference).
//   Q=xs@wqs^T, Km=xf@wkf^T (fp32)       -> C_M = Q Km^T/16 (fp32, out[2]) + CMT bf16
//   Qf,Kf (bf16), VsT (bf16, transposed) via fp32 linears with bf16 epilogues
//   S = Qf Kf^T/16 (MFMA bf16 -> bf16)   -> entmax rows -> P (bf16, in place)
//   BT = P @ SsT^T (MFMA -> fp32)        == bias_F^T
//   AfT = entmax(CMT + log(max(BT,1e-6))) rows (bf16)
//   T1 = AfT @ VsT^T (MFMA -> fp32); out1 = T1@wof^T+bof; out0 = out1 + LN(xf)
// ---------------------------------------------------------------------------

typedef __attribute__((ext_vector_type(8))) short short8;
typedef __attribute__((ext_vector_type(4))) float floatx4;

#define GLOBAL_AS __attribute__((address_space(1)))
#define LDS_AS    __attribute__((address_space(3)))

// ============================ fp32 vector GEMM =============================
#define BM 64
#define BN 64
#define BK 16

// TB==1: B is [N,K] row-major (C = A B^T). TB==0: B is [K,N] row-major.
// Epilogue options: C fp32 [row,col]; Cb bf16 [row,col];
// CbT bf16 per-batch transposed: [(row/RB)][col][row%RB]  (RB rows per batch).
template <int TB>
__global__ __launch_bounds__(256) void gemm_kernel(
    const float* __restrict__ A, const float* __restrict__ B,
    const float* __restrict__ bias, float* __restrict__ C,
    __hip_bfloat16* __restrict__ Cb, __hip_bfloat16* __restrict__ CbT,
    int M, int N, int K,
    long sA, long sB, long sC, long sCbT, int RB, float scale)
{
    const int bz = blockIdx.z;
    A += (long)bz * sA;
    B += (long)bz * sB;
    if (C)   C   += (long)bz * sC;
    if (CbT) CbT += (long)bz * sCbT;

    const int m0 = blockIdx.x * BM;
    const int n0 = blockIdx.y * BN;

    __shared__ float As[BK][BM + 4];
    __shared__ float Bs[BK][BN + 4];

    const int tid = threadIdx.x;
    const int tx = tid & 15;
    const int ty = tid >> 4;

    float acc[4][4] = {};

    for (int k0 = 0; k0 < K; k0 += BK) {
        {
            const int lk = tid & 15;
            const int lm = (tid >> 4) << 2;
            const float* Ap = A + (long)(m0 + lm) * K + (k0 + lk);
#pragma unroll
            for (int i = 0; i < 4; ++i) As[lk][lm + i] = Ap[(long)i * K];
        }
        if (TB == 1) {
            const int lk = tid & 15;
            const int ln = (tid >> 4) << 2;
            const float* Bp = B + (long)(n0 + ln) * K + (k0 + lk);
#pragma unroll
            for (int i = 0; i < 4; ++i) Bs[lk][ln + i] = Bp[(long)i * K];
        } else {
            const int ln = tid & 63;
            const int lk = (tid >> 6) << 2;
            const float* Bp = B + (long)(k0 + lk) * N + (n0 + ln);
#pragma unroll
            for (int i = 0; i < 4; ++i) Bs[lk + i][ln] = Bp[(long)i * N];
        }
        __syncthreads();

#pragma unroll
        for (int k = 0; k < BK; ++k) {
            const float4 av = *reinterpret_cast<const float4*>(&As[k][ty << 2]);
            const float4 bv = *reinterpret_cast<const float4*>(&Bs[k][tx << 2]);
            const float a[4] = {av.x, av.y, av.z, av.w};
            const float b[4] = {bv.x, bv.y, bv.z, bv.w};
#pragma unroll
            for (int i = 0; i < 4; ++i)
#pragma unroll
                for (int j = 0; j < 4; ++j) acc[i][j] += a[i] * b[j];
        }
        __syncthreads();
    }

#pragma unroll
    for (int i = 0; i < 4; ++i) {
        const int row = m0 + (ty << 2) + i;
#pragma unroll
        for (int j = 0; j < 4; ++j) {
            const int col = n0 + (tx << 2) + j;
            float v = acc[i][j] * scale;
            if (bias) v += bias[col];
            if (C)  C[(long)row * N + col] = v;
            if (Cb) Cb[(long)row * N + col] = (__hip_bfloat16)v;
            if (CbT) {
                const long b_i = row / RB, r_i = row % RB;
                CbT[b_i * (long)N * RB + (long)col * RB + r_i] = (__hip_bfloat16)v;
            }
        }
    }
}

// ============================ bf16 MFMA GEMM ===============================
// C[M,N] = scale * A[M,K] @ Bt[N,K]^T ; per-batch strides sA,sB,sC (elements).
// 128x128 tile, BK=64, 4 waves (2x2 of 64x64), 16x16x32 MFMA.
#define MT 128
#define NT 128
#define KT 64

template <typename OutT>
__global__ __launch_bounds__(256) void mfma_gemm(
    const __hip_bfloat16* __restrict__ A, const __hip_bfloat16* __restrict__ Bt,
    OutT* __restrict__ C, int M, int N, int K,
    long sA, long sB, long sC, float scale)
{
    __shared__ __hip_bfloat16 Asm[MT * KT];  // [128][64] row-major, 16 KB
    __shared__ __hip_bfloat16 Bsm[NT * KT];  // 16 KB

    const int bz = blockIdx.z;
    const short* Ag = (const short*)(A + (long)bz * sA);
    const short* Bg = (const short*)(Bt + (long)bz * sB);
    OutT* Cg = C + (long)bz * sC;

    const int m0 = blockIdx.x * MT;
    const int n0 = blockIdx.y * NT;

    const int tid  = threadIdx.x;
    const int lane = tid & 63;
    const int wm   = (tid >> 6 & 1) * 64;   // wave m-offset
    const int wn   = (tid >> 7) * 64;       // wave n-offset
    const int lm   = lane & 15;
    const int quad = lane >> 4;

    floatx4 acc[4][4] = {};

    for (int k0 = 0; k0 < K; k0 += KT) {
        // stage 2x16KB: 1024 16B-chunks each, 4 passes x 256 lanes.
        // chunk idx -> row = idx>>3, c8 = idx&7 ; LDS byte off = idx*16
        // (wave-uniform base + lane*16 as global_load_lds requires)
#pragma unroll
        for (int p = 0; p < 4; ++p) {
            const int idx = p * 256 + tid;
            const int row = idx >> 3;
            const int c8  = idx & 7;
            const int wbase = (p * 256 + (tid & 192)) * 16;  // wave-uniform
            __builtin_amdgcn_global_load_lds(
                (const GLOBAL_AS void*)(Ag + (long)(m0 + row) * K + k0 + c8 * 8),
                (LDS_AS void*)((char*)Asm + wbase), 16, 0, 0);
            __builtin_amdgcn_global_load_lds(
                (const GLOBAL_AS void*)(Bg + (long)(n0 + row) * K + k0 + c8 * 8),
                (LDS_AS void*)((char*)Bsm + wbase), 16, 0, 0);
        }
        __syncthreads();

#pragma unroll
        for (int ks = 0; ks < KT / 32; ++ks) {
            short8 af[4], bf[4];
#pragma unroll
            for (int i = 0; i < 4; ++i) {
                af[i] = *(const short8*)((const short*)Asm + (wm + i * 16 + lm) * KT + ks * 32 + quad * 8);
                bf[i] = *(const short8*)((const short*)Bsm + (wn + i * 16 + lm) * KT + ks * 32 + quad * 8);
            }
#pragma unroll
            for (int i = 0; i < 4; ++i)
#pragma unroll
                for (int j = 0; j < 4; ++j)
                    acc[i][j] = __builtin_amdgcn_mfma_f32_16x16x32_bf16(af[i], bf[j], acc[i][j], 0, 0, 0);
        }
        __syncthreads();
    }

    // C/D layout: col = lane&15 (+j*16), row = quad*4 + r (+i*16)
#pragma unroll
    for (int i = 0; i < 4; ++i)
#pragma unroll
        for (int r = 0; r < 4; ++r) {
            const int row = m0 + wm + i * 16 + quad * 4 + r;
            OutT* Cp = Cg + (long)row * N + n0 + wn + lm;
#pragma unroll
            for (int j = 0; j < 4; ++j)
                Cp[j * 16] = (OutT)(acc[i][j][r] * scale);
        }
}

// ======================= transpose fp32 -> bf16 ============================
// src [bz][R][C] fp32 -> dst [bz][C][R] bf16
__global__ __launch_bounds__(256) void transpose_to_bf16(
    const float* __restrict__ src, __hip_bfloat16* __restrict__ dst, int R, int C)
{
    __shared__ float t[32][33];
    const long bo = (long)blockIdx.z * R * C;
    const int tx = threadIdx.x & 31;
    const int ty = threadIdx.x >> 5;  // 0..7
    const int c0 = blockIdx.x * 32;
    const int r0 = blockIdx.y * 32;
#pragma unroll
    for (int j = 0; j < 4; ++j)
        t[ty + j * 8][tx] = src[bo + (long)(r0 + ty + j * 8) * C + c0 + tx];
    __syncthreads();
#pragma unroll
    for (int j = 0; j < 4; ++j)
        dst[bo + (long)(c0 + ty + j * 8) * R + r0 + tx] = (__hip_bfloat16)t[tx][ty + j * 8];
}

// ============================== entmax-1.5 =================================
// Row-wise entmax15 over length-L rows. z = In (+ log(max(Bias,1e-6)) if Bias).
// Newton on f(tau)=sum relu((z-mx)/2 - tau)^2 = 1 from tau=-1 (monotone).
template <typename InT, typename OutT>
__global__ __launch_bounds__(256) void entmax_kernel(
    const InT* __restrict__ Zin, const float* __restrict__ Bias,
    OutT* __restrict__ Out, int L)
{
    extern __shared__ float zb[];
    __shared__ float rbuf[8];
    const int tid = threadIdx.x;
    const long base = (long)blockIdx.x * L;

    float lmax = -3.4e38f;
    for (int i = tid; i < L; i += 256) {
        float z = (float)Zin[base + i];
        if (Bias) z += logf(fmaxf(Bias[base + i], 1e-6f));
        zb[i] = z;
        lmax = fmaxf(lmax, z);
    }
    for (int o = 32; o > 0; o >>= 1) lmax = fmaxf(lmax, __shfl_down(lmax, o));
    if ((tid & 63) == 0) rbuf[tid >> 6] = lmax;
    __syncthreads();
    const float mx = fmaxf(fmaxf(rbuf[0], rbuf[1]), fmaxf(rbuf[2], rbuf[3]));

    for (int i = tid; i < L; i += 256) zb[i] = (zb[i] - mx) * 0.5f;
    __syncthreads();

    float tau = -1.0f;
    for (int it = 0; it < 40; ++it) {
        float f = 0.f, g = 0.f;
        for (int i = tid; i < L; i += 256) {
            float d = fmaxf(zb[i] - tau, 0.f);
            f += d * d;
            g += d;
        }
        for (int o = 32; o > 0; o >>= 1) {
            f += __shfl_down(f, o);
            g += __shfl_down(g, o);
        }
        __syncthreads();
        if ((tid & 63) == 0) {
            rbuf[(tid >> 6) * 2] = f;
            rbuf[(tid >> 6) * 2 + 1] = g;
        }
        __syncthreads();
        f = rbuf[0] + rbuf[2] + rbuf[4] + rbuf[6];
        g = rbuf[1] + rbuf[3] + rbuf[5] + rbuf[7];
        if (g <= 0.f) break;
        const float step = (f - 1.0f) / (2.0f * g);
        tau += step;
        if (fabsf(step) < 1e-8f) break;
    }

    for (int i = tid; i < L; i += 256) {
        const float d = fmaxf(zb[i] - tau, 0.f);
        Out[base + i] = (OutT)(d * d);
    }
}

// ===================== out0 = xfo + LayerNorm(xf) ==========================
__global__ __launch_bounds__(256) void ln_add_kernel(
    const float* __restrict__ xf, const float* __restrict__ gam,
    const float* __restrict__ bet, const float* __restrict__ xfo,
    float* __restrict__ out0)
{
    __shared__ float rbuf[4];
    const int tid = threadIdx.x;
    const long base = (long)blockIdx.x * 256;
    const float x = xf[base + tid];

    float s = x;
    for (int o = 32; o > 0; o >>= 1) s += __shfl_down(s, o);
    if ((tid & 63) == 0) rbuf[tid >> 6] = s;
    __syncthreads();
    const float mu = (rbuf[0] + rbuf[1] + rbuf[2] + rbuf[3]) * (1.0f / 256.0f);
    const float d = x - mu;

    float v = d * d;
    for (int o = 32; o > 0; o >>= 1) v += __shfl_down(v, o);
    __syncthreads();
    if ((tid & 63) == 0) rbuf[tid >> 6] = v;
    __syncthreads();
    const float var = (rbuf[0] + rbuf[1] + rbuf[2] + rbuf[3]) * (1.0f / 256.0f);

    const float ln = d * rsqrtf(var + 1e-5f) * gam[tid] + bet[tid];
    out0[base + tid] = xfo[base + tid] + ln;
}

// ================================ driver ===================================
extern "C" void kernel_launch(void* const* d_in, const int* in_sizes, int n_in,
                              void* d_out, int out_size, void* d_ws, size_t ws_size,
                              hipStream_t stream)
{
    (void)in_sizes; (void)n_in; (void)out_size; (void)ws_size;

    const float* xs      = (const float*)d_in[0];
    const float* xf      = (const float*)d_in[1];
    const float* xs_fine = (const float*)d_in[2];
    const float* S_s     = (const float*)d_in[4];
    const float* cfa_wq  = (const float*)d_in[6];
    const float* cfa_bq  = (const float*)d_in[7];
    const float* cfa_wk  = (const float*)d_in[8];
    const float* cfa_bk  = (const float*)d_in[9];
    const float* wqs     = (const float*)d_in[14];
    const float* bqs     = (const float*)d_in[15];
    const float* wkf     = (const float*)d_in[16];
    const float* bkf     = (const float*)d_in[17];
    const float* wvs     = (const float*)d_in[18];
    const float* bvs     = (const float*)d_in[19];
    const float* wof     = (const float*)d_in[24];
    const float* bof     = (const float*)d_in[25];
    const float* fn_g    = (const float*)d_in[28];
    const float* fn_b    = (const float*)d_in[29];

    // workspace (216 MiB peak; round-1 proved >=224 MiB available)
    char* w = (char*)d_ws;
    __hip_bfloat16* Sb   = (__hip_bfloat16*)(w);                        // 64 MB; P in-place
    __hip_bfloat16* SsTb = (__hip_bfloat16*)(w + (64ll  << 20));        // 64 MB
    float*          BT   = (float*)         (w + (128ll << 20));        // 32 MB
    __hip_bfloat16* CMT  = (__hip_bfloat16*)(w + (160ll << 20));        // 16 MB
    __hip_bfloat16* Kfb  = (__hip_bfloat16*)(w + (176ll << 20));        // 16 MB
    float*          Q    = (float*)         (w + (192ll << 20));        //  8 MB
    float*          Km   = (float*)         (w + (200ll << 20));        //  8 MB
    __hip_bfloat16* Qfb  = (__hip_bfloat16*)(w + (208ll << 20));        //  4 MB
    __hip_bfloat16* VsTb = (__hip_bfloat16*)(w + (212ll << 20));        //  4 MB
    __hip_bfloat16* AfTb = Kfb;   // Kf dead after scores MFMA
    float*          T1   = Q;     // Q dead after C_M GEMM

    float* out0 = (float*)d_out;
    float* out1 = out0 + 2097152;
    float* outC = out0 + 4194304;

    const dim3 blk(256);

    // S_s [8,4096,1024] fp32 -> SsTb [8,1024,4096] bf16
    transpose_to_bf16<<<dim3(32, 128, 8), blk, 0, stream>>>(S_s, SsTb, 4096, 1024);

    // linears
    gemm_kernel<1><<<dim3(128, 4, 1), blk, 0, stream>>>(xs, wqs, bqs, Q, nullptr, nullptr,
        8192, 256, 256, 0, 0, 0, 0, 1024, 1.f);
    gemm_kernel<1><<<dim3(128, 4, 1), blk, 0, stream>>>(xf, wkf, bkf, Km, nullptr, nullptr,
        8192, 256, 256, 0, 0, 0, 0, 1024, 1.f);
    gemm_kernel<1><<<dim3(128, 4, 1), blk, 0, stream>>>(xs, wvs, bvs, nullptr, nullptr, VsTb,
        8192, 256, 256, 0, 0, 0, 0, 1024, 1.f);          // per-batch transposed bf16
    gemm_kernel<1><<<dim3(128, 4, 1), blk, 0, stream>>>(xf, cfa_wq, cfa_bq, nullptr, Qfb, nullptr,
        8192, 256, 256, 0, 0, 0, 0, 1024, 1.f);
    gemm_kernel<1><<<dim3(512, 4, 1), blk, 0, stream>>>(xs_fine, cfa_wk, cfa_bk, nullptr, Kfb, nullptr,
        32768, 256, 256, 0, 0, 0, 0, 1024, 1.f);

    // C_M = Q Km^T / 16 -> out[2] fp32 + CMT bf16 (per-batch transposed)
    gemm_kernel<1><<<dim3(16, 16, 8), blk, 0, stream>>>(Q, Km, nullptr, outC, nullptr, CMT,
        1024, 1024, 256, 262144, 262144, 1048576, 1048576, 1024, 0.0625f);

    // scores = Qf Kf^T / 16 -> Sb bf16 [8,1024,4096]
    mfma_gemm<__hip_bfloat16><<<dim3(8, 32, 8), blk, 0, stream>>>(Qfb, Kfb, Sb,
        1024, 4096, 256, 262144, 1048576, 4194304, 0.0625f);

    // P = entmax15 rows (in place, bf16)
    entmax_kernel<__hip_bfloat16, __hip_bfloat16><<<dim3(8192), blk, 4096 * 4, stream>>>(
        Sb, nullptr, Sb, 4096);

    // BT = P @ S_s  (== bias_F^T) fp32
    mfma_gemm<float><<<dim3(8, 8, 8), blk, 0, stream>>>(Sb, SsTb, BT,
        1024, 1024, 4096, 4194304, 4194304, 1048576, 1.f);

    // AfT = entmax15(CMT + log(max(BT,1e-6))) rows -> bf16
    entmax_kernel<__hip_bfloat16, __hip_bfloat16><<<dim3(8192), blk, 1024 * 4, stream>>>(
        CMT, BT, AfTb, 1024);

    // T1 = AfT @ Vs fp32
    mfma_gemm<float><<<dim3(8, 2, 8), blk, 0, stream>>>(AfTb, VsTb, T1,
        1024, 256, 1024, 1048576, 262144, 262144, 1.f);

    // out1 = T1 @ wof^T + bof
    gemm_kernel<1><<<dim3(128, 4, 1), blk, 0, stream>>>(T1, wof, bof, out1, nullptr, nullptr,
        8192, 256, 256, 0, 0, 0, 0, 1024, 1.f);

    // out0 = out1 + LayerNorm(xf)
    ln_add_kernel<<<dim3(8192), blk, 0, stream>>>(xf, fn_g, fn_b, out1, out0);
}

// Round 3
// 780.326 us; speedup vs baseline: 2.4983x; 1.2498x over previous
//
#include <hip/hip_runtime.h>
#include <hip/hip_bf16.h>

// ---------------------------------------------------------------------------
// Hie_Couple live subgraph (xs_/A_s/C_M_S/bias_S/Vf dead in reference).
// All GEMMs on bf16 MFMA. entmax-1.5 via register-resident Newton.
// ---------------------------------------------------------------------------

typedef __attribute__((ext_vector_type(8))) short short8;
typedef __attribute__((ext_vector_type(4))) float floatx4;

#define GLOBAL_AS __attribute__((address_space(1)))
#define LDS_AS    __attribute__((address_space(3)))

struct alignas(4) bf2 { __hip_bfloat16 x, y; };
struct alignas(8) bf4 { __hip_bfloat16 v[4]; };

// ============================ bf16 MFMA GEMM ===============================
// C[M,N] = scale * A[M,K] @ Bt[N,K]^T (+ bias[col]); strides per blockIdx.z.
// Optional CT: bf16, per-RB-row-group transposed:
//   CT[bz*sCT + (row/RB)*N*RB + col*RB + row%RB]
// 128x128 tile, BK=64, 4 waves (2x2 of 64x64), 16x16x32 MFMA.
#define MT 128
#define NT 128
#define KT 64

template <typename OutT>
__global__ __launch_bounds__(256) void mfma_gemm(
    const __hip_bfloat16* __restrict__ A, const __hip_bfloat16* __restrict__ Bt,
    const float* __restrict__ bias, OutT* __restrict__ C,
    __hip_bfloat16* __restrict__ CT,
    int M, int N, int K,
    long sA, long sB, long sC, long sCT, int RB, float scale)
{
    __shared__ __hip_bfloat16 Asm[MT * KT];  // 16 KB
    __shared__ __hip_bfloat16 Bsm[NT * KT];  // 16 KB

    const int bz = blockIdx.z;
    const short* Ag = (const short*)(A + (long)bz * sA);
    const short* Bg = (const short*)(Bt + (long)bz * sB);

    const int m0 = blockIdx.x * MT;
    const int n0 = blockIdx.y * NT;

    const int tid  = threadIdx.x;
    const int lane = tid & 63;
    const int wm   = (tid >> 6 & 1) * 64;   // wave m-offset
    const int wn   = (tid >> 7) * 64;       // wave n-offset
    const int lm   = lane & 15;
    const int quad = lane >> 4;

    floatx4 acc[4][4] = {};

    for (int k0 = 0; k0 < K; k0 += KT) {
        // stage 2x16KB: 1024 16B-chunks each, 4 passes x 256 lanes
#pragma unroll
        for (int p = 0; p < 4; ++p) {
            const int idx = p * 256 + tid;
            const int row = idx >> 3;
            const int c8  = idx & 7;
            const int wbase = (p * 256 + (tid & 192)) * 16;  // wave-uniform base
            __builtin_amdgcn_global_load_lds(
                (const GLOBAL_AS void*)(Ag + (long)(m0 + row) * K + k0 + c8 * 8),
                (LDS_AS void*)((char*)Asm + wbase), 16, 0, 0);
            __builtin_amdgcn_global_load_lds(
                (const GLOBAL_AS void*)(Bg + (long)(n0 + row) * K + k0 + c8 * 8),
                (LDS_AS void*)((char*)Bsm + wbase), 16, 0, 0);
        }
        __syncthreads();

#pragma unroll
        for (int ks = 0; ks < KT / 32; ++ks) {
            short8 af[4], bf[4];
#pragma unroll
            for (int i = 0; i < 4; ++i) {
                af[i] = *(const short8*)((const short*)Asm + (wm + i * 16 + lm) * KT + ks * 32 + quad * 8);
                bf[i] = *(const short8*)((const short*)Bsm + (wn + i * 16 + lm) * KT + ks * 32 + quad * 8);
            }
#pragma unroll
            for (int i = 0; i < 4; ++i)
#pragma unroll
                for (int j = 0; j < 4; ++j)
                    acc[i][j] = __builtin_amdgcn_mfma_f32_16x16x32_bf16(af[i], bf[j], acc[i][j], 0, 0, 0);
        }
        __syncthreads();
    }

    // C/D layout: col = lane&15 (+j*16 + wn), row = quad*4 + r (+i*16 + wm)
    float bb[4] = {0.f, 0.f, 0.f, 0.f};
    if (bias) {
#pragma unroll
        for (int j = 0; j < 4; ++j) bb[j] = bias[n0 + wn + lm + j * 16];
    }
    OutT* Cg = C ? C + (long)bz * sC : nullptr;
    __hip_bfloat16* CTg = CT ? CT + (long)bz * sCT : nullptr;

#pragma unroll
    for (int i = 0; i < 4; ++i) {
        const int row0 = m0 + wm + i * 16 + quad * 4;
#pragma unroll
        for (int j = 0; j < 4; ++j) {
            const int col = n0 + wn + lm + j * 16;
            float v[4];
#pragma unroll
            for (int r = 0; r < 4; ++r) v[r] = acc[i][j][r] * scale + bb[j];
            if (Cg) {
#pragma unroll
                for (int r = 0; r < 4; ++r)
                    Cg[(long)(row0 + r) * N + col] = (OutT)v[r];
            }
            if (CTg) {
                bf4 pk;
#pragma unroll
                for (int r = 0; r < 4; ++r) pk.v[r] = (__hip_bfloat16)v[r];
                const long b_i = row0 / RB, r_i = row0 % RB;
                *(bf4*)(CTg + b_i * (long)N * RB + (long)col * RB + r_i) = pk;
            }
        }
    }
}

// ======================= fp32 -> bf16 converters ===========================
__global__ __launch_bounds__(256) void convert_bf16(
    const float* __restrict__ src, __hip_bfloat16* __restrict__ dst)
{
    const long g = ((long)blockIdx.x * 256 + threadIdx.x) * 4;
    const float4 v = *(const float4*)(src + g);
    bf4 o;
    o.v[0] = (__hip_bfloat16)v.x; o.v[1] = (__hip_bfloat16)v.y;
    o.v[2] = (__hip_bfloat16)v.z; o.v[3] = (__hip_bfloat16)v.w;
    *(bf4*)(dst + g) = o;
}

// 6 weights [256,256] -> contiguous bf16 slots of 65536
__global__ __launch_bounds__(256) void convert_w6(
    const float* w0, const float* w1, const float* w2,
    const float* w3, const float* w4, const float* w5,
    __hip_bfloat16* __restrict__ dst)
{
    const float* srcs[6] = {w0, w1, w2, w3, w4, w5};
    const float* s = srcs[blockIdx.y];
    const long off = (long)blockIdx.y * 65536;
    const long g = ((long)blockIdx.x * 256 + threadIdx.x) * 4;
    const float4 v = *(const float4*)(s + g);
    bf4 o;
    o.v[0] = (__hip_bfloat16)v.x; o.v[1] = (__hip_bfloat16)v.y;
    o.v[2] = (__hip_bfloat16)v.z; o.v[3] = (__hip_bfloat16)v.w;
    *(bf4*)(dst + off + g) = o;
}

// src [bz][R][C] fp32 -> dst [bz][C][R] bf16
__global__ __launch_bounds__(256) void transpose_to_bf16(
    const float* __restrict__ src, __hip_bfloat16* __restrict__ dst, int R, int C)
{
    __shared__ float t[32][33];
    const long bo = (long)blockIdx.z * R * C;
    const int tx = threadIdx.x & 31;
    const int ty = threadIdx.x >> 5;  // 0..7
    const int c0 = blockIdx.x * 32;
    const int r0 = blockIdx.y * 32;
#pragma unroll
    for (int j = 0; j < 4; ++j)
        t[ty + j * 8][tx] = src[bo + (long)(r0 + ty + j * 8) * C + c0 + tx];
    __syncthreads();
#pragma unroll
    for (int j = 0; j < 4; ++j)
        dst[bo + (long)(c0 + ty + j * 8) * R + r0 + tx] = (__hip_bfloat16)t[tx][ty + j * 8];
}

// ============================== entmax-1.5 =================================
// Register-resident: row of L = EPT*256 bf16 in EPT VGPRs/thread.
// z = Zin (+ log(max(Bias,1e-6)) if HB). Newton on
// f(tau) = sum relu((z-mx)/2 - tau)^2 = 1 from tau = -1 (monotone, no overshoot).
template <int EPT, bool HB>
__global__ __launch_bounds__(256) void entmax_reg(
    const __hip_bfloat16* __restrict__ Zin, const float* __restrict__ Bias,
    __hip_bfloat16* __restrict__ Out)
{
    constexpr int L = EPT * 256;
    constexpr int NP = EPT / 2;
    __shared__ float rbuf[8];
    const int tid = threadIdx.x;
    const long base = (long)blockIdx.x * L;

    float z[EPT];
    float lmax = -3.4e38f;
    const unsigned short* Zp = (const unsigned short*)(Zin + base);
#pragma unroll
    for (int e = 0; e < NP; ++e) {
        const int idx = (tid + e * 256) * 2;
        const unsigned int u = *(const unsigned int*)(Zp + idx);
        float a = __uint_as_float(u << 16);
        float b = __uint_as_float(u & 0xffff0000u);
        if (HB) {
            const float2 bv = *(const float2*)(Bias + base + idx);
            a += logf(fmaxf(bv.x, 1e-6f));
            b += logf(fmaxf(bv.y, 1e-6f));
        }
        z[2 * e] = a; z[2 * e + 1] = b;
        lmax = fmaxf(lmax, fmaxf(a, b));
    }
    for (int o = 32; o > 0; o >>= 1) lmax = fmaxf(lmax, __shfl_down(lmax, o));
    if ((tid & 63) == 0) rbuf[tid >> 6] = lmax;
    __syncthreads();
    const float mx = fmaxf(fmaxf(rbuf[0], rbuf[1]), fmaxf(rbuf[2], rbuf[3]));
#pragma unroll
    for (int e = 0; e < EPT; ++e) z[e] = (z[e] - mx) * 0.5f;

    float tau = -1.0f;
    for (int it = 0; it < 24; ++it) {
        float f = 0.f, g = 0.f;
#pragma unroll
        for (int e = 0; e < EPT; ++e) {
            const float d = fmaxf(z[e] - tau, 0.f);
            f = fmaf(d, d, f);
            g += d;
        }
        for (int o = 32; o > 0; o >>= 1) {
            f += __shfl_down(f, o);
            g += __shfl_down(g, o);
        }
        __syncthreads();
        if ((tid & 63) == 0) {
            rbuf[(tid >> 6) * 2] = f;
            rbuf[(tid >> 6) * 2 + 1] = g;
        }
        __syncthreads();
        f = rbuf[0] + rbuf[2] + rbuf[4] + rbuf[6];
        g = rbuf[1] + rbuf[3] + rbuf[5] + rbuf[7];
        if (g <= 0.f) break;
        const float step = (f - 1.0f) / (2.0f * g);
        tau += step;
        if (!(fabsf(step) > 1e-7f)) break;
    }

#pragma unroll
    for (int e = 0; e < NP; ++e) {
        const int idx = (tid + e * 256) * 2;
        const float d0 = fmaxf(z[2 * e] - tau, 0.f);
        const float d1 = fmaxf(z[2 * e + 1] - tau, 0.f);
        bf2 o;
        o.x = (__hip_bfloat16)(d0 * d0);
        o.y = (__hip_bfloat16)(d1 * d1);
        *(bf2*)(Out + base + idx) = o;
    }
}

// ===================== out0 = xfo + LayerNorm(xf) ==========================
__global__ __launch_bounds__(256) void ln_add_kernel(
    const float* __restrict__ xf, const float* __restrict__ gam,
    const float* __restrict__ bet, const float* __restrict__ xfo,
    float* __restrict__ out0)
{
    __shared__ float rbuf[4];
    const int tid = threadIdx.x;
    const long base = (long)blockIdx.x * 256;
    const float x = xf[base + tid];

    float s = x;
    for (int o = 32; o > 0; o >>= 1) s += __shfl_down(s, o);
    if ((tid & 63) == 0) rbuf[tid >> 6] = s;
    __syncthreads();
    const float mu = (rbuf[0] + rbuf[1] + rbuf[2] + rbuf[3]) * (1.0f / 256.0f);
    const float d = x - mu;

    float v = d * d;
    for (int o = 32; o > 0; o >>= 1) v += __shfl_down(v, o);
    __syncthreads();
    if ((tid & 63) == 0) rbuf[tid >> 6] = v;
    __syncthreads();
    const float var = (rbuf[0] + rbuf[1] + rbuf[2] + rbuf[3]) * (1.0f / 256.0f);

    const float ln = d * rsqrtf(var + 1e-5f) * gam[tid] + bet[tid];
    out0[base + tid] = xfo[base + tid] + ln;
}

// ================================ driver ===================================
extern "C" void kernel_launch(void* const* d_in, const int* in_sizes, int n_in,
                              void* d_out, int out_size, void* d_ws, size_t ws_size,
                              hipStream_t stream)
{
    (void)in_sizes; (void)n_in; (void)out_size; (void)ws_size;

    const float* xs      = (const float*)d_in[0];
    const float* xf      = (const float*)d_in[1];
    const float* xs_fine = (const float*)d_in[2];
    const float* S_s     = (const float*)d_in[4];
    const float* cfa_wq  = (const float*)d_in[6];
    const float* cfa_bq  = (const float*)d_in[7];
    const float* cfa_wk  = (const float*)d_in[8];
    const float* cfa_bk  = (const float*)d_in[9];
    const float* wqs     = (const float*)d_in[14];
    const float* bqs     = (const float*)d_in[15];
    const float* wkf     = (const float*)d_in[16];
    const float* bkf     = (const float*)d_in[17];
    const float* wvs     = (const float*)d_in[18];
    const float* bvs     = (const float*)d_in[19];
    const float* wof     = (const float*)d_in[24];
    const float* bof     = (const float*)d_in[25];
    const float* fn_g    = (const float*)d_in[28];
    const float* fn_b    = (const float*)d_in[29];

    // ---- workspace layout (MB offsets; peak ~217 MB, 224 MiB proven) ----
    char* w = (char*)d_ws;
    __hip_bfloat16* Sb   = (__hip_bfloat16*)(w);                   // 64 MB
    __hip_bfloat16* xsfb = (__hip_bfloat16*)(w);                   // 16 MB (dead before Sb written)
    __hip_bfloat16* SsTb = (__hip_bfloat16*)(w + (64ll  << 20));   // 64 MB
    __hip_bfloat16* AfTb = (__hip_bfloat16*)(w + (64ll  << 20));   // 16 MB (after BT gemm)
    float*          BT   = (float*)         (w + (128ll << 20));   // 32 MB
    __hip_bfloat16* CMT  = (__hip_bfloat16*)(w + (160ll << 20));   // 16 MB
    __hip_bfloat16* Kfb  = (__hip_bfloat16*)(w + (176ll << 20));   // 16 MB
    __hip_bfloat16* Qfb  = (__hip_bfloat16*)(w + (192ll << 20));   //  4 MB
    __hip_bfloat16* Qb   = (__hip_bfloat16*)(w + (196ll << 20));   //  4 MB
    __hip_bfloat16* T1b  = Qb;                                     //  (after C_M)
    __hip_bfloat16* Kmb  = (__hip_bfloat16*)(w + (200ll << 20));   //  4 MB
    __hip_bfloat16* VsTb = (__hip_bfloat16*)(w + (204ll << 20));   //  4 MB
    __hip_bfloat16* xsb  = (__hip_bfloat16*)(w + (208ll << 20));   //  4 MB
    __hip_bfloat16* xfb  = (__hip_bfloat16*)(w + (212ll << 20));   //  4 MB
    __hip_bfloat16* wb   = (__hip_bfloat16*)(w + (216ll << 20));   //  0.75 MB
    __hip_bfloat16* wqs_b = wb;
    __hip_bfloat16* wkf_b = wb + 65536;
    __hip_bfloat16* wvs_b = wb + 131072;
    __hip_bfloat16* cwq_b = wb + 196608;
    __hip_bfloat16* cwk_b = wb + 262144;
    __hip_bfloat16* wof_b = wb + 327680;

    float* out0 = (float*)d_out;
    float* out1 = out0 + 2097152;
    float* outC = out0 + 4194304;

    const dim3 blk(256);

    // ---- conversions ----
    convert_bf16<<<dim3(2048), blk, 0, stream>>>(xs, xsb);
    convert_bf16<<<dim3(2048), blk, 0, stream>>>(xf, xfb);
    convert_bf16<<<dim3(8192), blk, 0, stream>>>(xs_fine, xsfb);
    convert_w6<<<dim3(64, 6), blk, 0, stream>>>(wqs, wkf, wvs, cfa_wq, cfa_wk, wof, wb);
    // S_s [8,4096,1024] fp32 -> SsTb [8,1024,4096] bf16
    transpose_to_bf16<<<dim3(32, 128, 8), blk, 0, stream>>>(S_s, SsTb, 4096, 1024);

    // ---- linears (MFMA): Y = X @ W^T + b ----
    mfma_gemm<__hip_bfloat16><<<dim3(64, 2, 1), blk, 0, stream>>>(xsb, wqs_b, bqs,
        Qb, nullptr, 8192, 256, 256, 0, 0, 0, 0, 1024, 1.f);
    mfma_gemm<__hip_bfloat16><<<dim3(64, 2, 1), blk, 0, stream>>>(xfb, wkf_b, bkf,
        Kmb, nullptr, 8192, 256, 256, 0, 0, 0, 0, 1024, 1.f);
    mfma_gemm<float><<<dim3(64, 2, 1), blk, 0, stream>>>(xsb, wvs_b, bvs,
        (float*)nullptr, VsTb, 8192, 256, 256, 0, 0, 0, 0, 1024, 1.f);  // Vs^T per batch
    mfma_gemm<__hip_bfloat16><<<dim3(64, 2, 1), blk, 0, stream>>>(xfb, cwq_b, cfa_bq,
        Qfb, nullptr, 8192, 256, 256, 0, 0, 0, 0, 1024, 1.f);
    mfma_gemm<__hip_bfloat16><<<dim3(256, 2, 1), blk, 0, stream>>>(xsfb, cwk_b, cfa_bk,
        Kfb, nullptr, 32768, 256, 256, 0, 0, 0, 0, 1024, 1.f);

    // ---- C_M = Q Km^T / 16 -> out[2] fp32 + CMT bf16 (per-batch transposed) ----
    mfma_gemm<float><<<dim3(8, 8, 8), blk, 0, stream>>>(Qb, Kmb, nullptr,
        outC, CMT, 1024, 1024, 256, 262144, 262144, 1048576, 1048576, 1024, 0.0625f);

    // ---- scores = Qf Kf^T / 16 -> Sb bf16 [8,1024,4096] ----
    mfma_gemm<__hip_bfloat16><<<dim3(8, 32, 8), blk, 0, stream>>>(Qfb, Kfb, nullptr,
        Sb, nullptr, 1024, 4096, 256, 262144, 1048576, 4194304, 0, 1024, 0.0625f);

    // ---- P = entmax15 rows (in place) ----
    entmax_reg<16, false><<<dim3(8192), blk, 0, stream>>>(Sb, nullptr, Sb);

    // ---- BT = P @ S_s (== bias_F^T) fp32 ----
    mfma_gemm<float><<<dim3(8, 8, 8), blk, 0, stream>>>(Sb, SsTb, nullptr,
        BT, nullptr, 1024, 1024, 4096, 4194304, 4194304, 1048576, 0, 1024, 1.f);

    // ---- AfT = entmax15(CMT + log(max(BT,1e-6))) rows -> bf16 ----
    entmax_reg<4, true><<<dim3(8192), blk, 0, stream>>>(CMT, BT, AfTb);

    // ---- T1 = AfT @ Vs -> bf16 ----
    mfma_gemm<__hip_bfloat16><<<dim3(8, 2, 8), blk, 0, stream>>>(AfTb, VsTb, nullptr,
        T1b, nullptr, 1024, 256, 1024, 1048576, 262144, 262144, 0, 1024, 1.f);

    // ---- out1 = T1 @ wof^T + bof ----
    mfma_gemm<float><<<dim3(64, 2, 1), blk, 0, stream>>>(T1b, wof_b, bof,
        out1, nullptr, 8192, 256, 256, 0, 0, 0, 0, 1024, 1.f);

    // ---- out0 = out1 + LayerNorm(xf) ----
    ln_add_kernel<<<dim3(8192), blk, 0, stream>>>(xf, fn_g, fn_b, out1, out0);
}